// Round 6
// baseline (934.196 us; speedup 1.0000x reference)
//
#include <hip/hip_runtime.h>
#include <hip/hip_bf16.h>

// ---------------------------------------------------------------------------
// Performer (FAVOR+) attention, MI355X gfx950.
// R6: inputs/outputs are FLOAT32 (reference dtype). Internal compute bf16
// MFMA. x is converted f32->bf16 inside the GEMM staging (AF32 path);
// weights/proj converted during prep. Output + bias in f32.
// Workspace-lean chunked design (~162 MB, known to fit):
//   prep:  wqt,wkt,wvt,wot = bf16(W^T); projb = bf16(proj) padded to 288 rows
//   S1:    Qb,Kb,Vb (16384x1024 bf16) = x(f32) . W^T      (AF32 GEMM, EPI0)
//   phase A, per n-chunk c (1024 rows x 4):
//     S2k: kptc[bh](288x1024) = relu(projb . K_c^T)+eps, rows>=266 -> 0 (EPI2)
//     vtc[bh](65x1024)        = [V_c^T ; ones]
//     S3:  kvxf[bh](65x288)  += vtc . kptc^T  f32 accumulate (EPI6)
//   finalize: kvxb = bf16(kvxf)
//   phase B, per chunk c:
//     S2q: qpc[bh](1024x288) = relu(Q_c . projb^T)+eps, cols>=266 -> 0 (EPI1)
//     S4:  outm rows c       = (qpc . kvxb^T)/denom, merged heads (EPI4)
//   S5:    out(f32) = outm . wot^T + bo (EPI5)
// outm aliases Kb; qpc aliases kptc.  GEMM: NT bf16 MFMA 16x16x32, 128x128
// tile, 256 thr, BK=32, chunk-major LDS, register staging.
// ---------------------------------------------------------------------------

typedef __bf16 bf16x8 __attribute__((ext_vector_type(8)));
typedef float  f32x4  __attribute__((ext_vector_type(4)));

#define EPS_F 1e-3f

// 8 contiguous f32 -> 8 bf16 packed in a uint4 (RNE via __hip_bfloat16 cast)
__device__ __forceinline__ uint4 cvt8(const float* __restrict__ p) {
  const float4 f0 = *(const float4*)p;
  const float4 f1 = *(const float4*)(p + 4);
  union { __hip_bfloat16 h[8]; uint4 u; } r;
  r.h[0] = (__hip_bfloat16)f0.x; r.h[1] = (__hip_bfloat16)f0.y;
  r.h[2] = (__hip_bfloat16)f0.z; r.h[3] = (__hip_bfloat16)f0.w;
  r.h[4] = (__hip_bfloat16)f1.x; r.h[5] = (__hip_bfloat16)f1.y;
  r.h[6] = (__hip_bfloat16)f1.z; r.h[7] = (__hip_bfloat16)f1.w;
  return r.u;
}

// EPI: 0 bf16 store | 1 relu+eps, col>=266 -> 0 | 2 relu+eps, row>=266 -> 0 |
//      4 divide by col-64 denom, store bf16 | 5 +bias f32 store | 6 f32 +=
// AF32: A operand is f32 (converted to bf16 during staging)
template <int EPI, bool AF32>
__global__ void __launch_bounds__(256, 2)
gemm_nt(const void* __restrict__ Ap, long lda, long sAb, long sAh,
        const __hip_bfloat16* __restrict__ Bt, long ldb, long sBb, long sBh,
        void* __restrict__ Cp, long ldc, long sCb, long sCh,
        int M, int N, int K, const float* __restrict__ bias) {
  __shared__ __align__(16) __hip_bfloat16 As[4096];  // 128x32 bf16, chunk-major
  __shared__ __align__(16) __hip_bfloat16 Bs[4096];
  __shared__ float Dsh[128];  // EPI4 denominator broadcast

  const int tid  = threadIdx.x;
  const int lane = tid & 63;
  const int wave = tid >> 6;
  const int quad = lane >> 4;
  const int l15  = lane & 15;
  const int wm   = wave >> 1;
  const int wn   = wave & 1;
  const int m0   = blockIdx.x * 128;
  const int n0   = blockIdx.y * 128;
  const int bz   = blockIdx.z;
  const int bb   = bz >> 4, hh = bz & 15;

  const long abase = (long)bb * sAb + (long)hh * sAh;
  Bt += (long)bb * sBb + (long)hh * sBh;

  // staging: thread t handles k-chunk plane cc=t>>7 (and cc+2), row mr=t&127
  const int  mr   = tid & 127;
  const int  cc   = tid >> 7;  // 0/1
  const long aoff = abase + (long)min(m0 + mr, M - 1) * lda + cc * 8;
  const long boff = (long)min(n0 + mr, N - 1) * ldb + cc * 8;
  char* AsB = (char*)As;
  char* BsB = (char*)Bs;
  const int ldst = tid * 16;

  f32x4 acc[4][4] = {};

  for (int k0 = 0; k0 < K; k0 += 32) {
    uint4 ra0, ra1;
    if constexpr (AF32) {
      const float* Af = (const float*)Ap;
      ra0 = cvt8(Af + aoff + k0);
      ra1 = cvt8(Af + aoff + k0 + 16);
    } else {
      const __hip_bfloat16* Ab = (const __hip_bfloat16*)Ap;
      ra0 = *(const uint4*)(Ab + aoff + k0);
      ra1 = *(const uint4*)(Ab + aoff + k0 + 16);
    }
    const uint4 rb0 = *(const uint4*)(Bt + boff + k0);
    const uint4 rb1 = *(const uint4*)(Bt + boff + k0 + 16);
    __syncthreads();  // previous iter's ds_reads complete before overwrite
    *(uint4*)(AsB + ldst)        = ra0;
    *(uint4*)(AsB + ldst + 4096) = ra1;
    *(uint4*)(BsB + ldst)        = rb0;
    *(uint4*)(BsB + ldst + 4096) = rb1;
    __syncthreads();  // stores visible to all waves

    const char* ap = (const char*)As + quad * 2048 + (wm * 64 + l15) * 16;
    const char* bp = (const char*)Bs + quad * 2048 + (wn * 64 + l15) * 16;
    bf16x8 af[4], bfr[4];
#pragma unroll
    for (int it = 0; it < 4; ++it) af[it] = *(const bf16x8*)(ap + it * 256);
#pragma unroll
    for (int jt = 0; jt < 4; ++jt) bfr[jt] = *(const bf16x8*)(bp + jt * 256);
#pragma unroll
    for (int it = 0; it < 4; ++it)
#pragma unroll
      for (int jt = 0; jt < 4; ++jt)
        acc[it][jt] = __builtin_amdgcn_mfma_f32_16x16x32_bf16(
            af[it], bfr[jt], acc[it][jt], 0, 0, 0);
  }
  __syncthreads();  // protect Dsh (EPI4) / uniform exit

  const long cbase = (long)bb * sCb + (long)hh * sCh;

  if constexpr (EPI == 4) {
    // denominator = col 64 -> wave wn==1, tile jt=0, lanes l15==0
    if (wn == 1 && l15 == 0) {
#pragma unroll
      for (int it = 0; it < 4; ++it)
#pragma unroll
        for (int i = 0; i < 4; ++i)
          Dsh[wm * 64 + it * 16 + quad * 4 + i] = acc[it][0][i];
    }
    __syncthreads();
    if (wn == 0) {  // cols 0..63 = HC dims
      __hip_bfloat16* C = (__hip_bfloat16*)Cp;
#pragma unroll
      for (int it = 0; it < 4; ++it) {
#pragma unroll
        for (int i = 0; i < 4; ++i) {
          const int   row = wm * 64 + it * 16 + quad * 4 + i;
          const float den = Dsh[row];
          // guarded reciprocal: bad denom -> finite wrong value, not NaN
          const float dinv = (den > 1e-30f) ? (1.0f / den) : 0.0f;
          const long  gm   = m0 + row;
#pragma unroll
          for (int jt = 0; jt < 4; ++jt) {
            const int col = jt * 16 + l15;
            C[cbase + gm * ldc + col] =
                (__hip_bfloat16)(acc[it][jt][i] * dinv);
          }
        }
      }
    }
  } else {
#pragma unroll
    for (int it = 0; it < 4; ++it) {
#pragma unroll
      for (int jt = 0; jt < 4; ++jt) {
#pragma unroll
        for (int i = 0; i < 4; ++i) {
          const int row = wm * 64 + it * 16 + quad * 4 + i;
          const int col = wn * 64 + jt * 16 + l15;
          const int gm = m0 + row, gn = n0 + col;
          if (gm < M && gn < N) {
            float v = acc[it][jt][i];
            if constexpr (EPI == 1) v = (gn < 266) ? (fmaxf(v, 0.f) + EPS_F) : 0.f;
            if constexpr (EPI == 2) v = (gm < 266) ? (fmaxf(v, 0.f) + EPS_F) : 0.f;
            if constexpr (EPI == 6) {
              ((float*)Cp)[cbase + (long)gm * ldc + gn] += v;
            } else if constexpr (EPI == 5) {
              ((float*)Cp)[cbase + (long)gm * ldc + gn] = v + bias[gn];
            } else {
              ((__hip_bfloat16*)Cp)[cbase + (long)gm * ldc + gn] = (__hip_bfloat16)v;
            }
          }
        }
      }
    }
  }
}

// dst[n*1024 + k] = bf16(src[k*1024 + n])  (1024x1024, f32 -> bf16)
__global__ void transpose_w(const float* __restrict__ src,
                            __hip_bfloat16* __restrict__ dst) {
  __shared__ float t[32][33];
  const int k0 = blockIdx.x * 32, n0 = blockIdx.y * 32;
  const int tx = threadIdx.x & 31, ty = threadIdx.x >> 5;
#pragma unroll
  for (int i = 0; i < 4; ++i)
    t[ty + i * 8][tx] = src[(long)(k0 + ty + i * 8) * 1024 + n0 + tx];
  __syncthreads();
#pragma unroll
  for (int i = 0; i < 4; ++i)
    dst[(long)(n0 + ty + i * 8) * 1024 + k0 + tx] =
        (__hip_bfloat16)t[tx][ty + i * 8];
}

// projb (288x64 bf16): rows<266 = bf16(proj), rows 266..287 exact zero.
// proj has exactly 266*64 f32 elements — no OOB read.
__global__ void prep_proj(const float* __restrict__ proj,
                          __hip_bfloat16* __restrict__ projb) {
  const int i = blockIdx.x * 256 + threadIdx.x;
  if (i < 288 * 64) {
    const int r = i >> 6;
    __hip_bfloat16 v = (__hip_bfloat16)0.f;
    if (r < 266) v = (__hip_bfloat16)proj[i];
    projb[i] = v;
  }
}

__global__ void zero_f32(float* __restrict__ p, int n) {
  const int i = blockIdx.x * 256 + threadIdx.x;
  if (i < n) p[i] = 0.f;
}

// kvxb = bf16(kvxf)
__global__ void finalize_kvx(const float* __restrict__ kvxf,
                             __hip_bfloat16* __restrict__ kvxb, int n) {
  const int i = blockIdx.x * 256 + threadIdx.x;
  if (i < n) kvxb[i] = (__hip_bfloat16)kvxf[i];
}

// vtc[bh](65x1024) = [V_chunk^T ; ones] from Vb rows c*1024..+1024
__global__ void build_vtc(const __hip_bfloat16* __restrict__ Vb,
                          __hip_bfloat16* __restrict__ vtc, int c) {
  __shared__ __hip_bfloat16 t[64 * 65];
  const int bh = blockIdx.y, n0 = blockIdx.x * 64;
  const int b = bh >> 4, h = bh & 15;
  const int tid = threadIdx.x;
  const __hip_bfloat16* src =
      Vb + ((long)b * 4096 + (long)c * 1024 + n0) * 1024 + h * 64;
  {
    const int d = tid & 63, nr = tid >> 6;
#pragma unroll
    for (int i = 0; i < 16; ++i) {
      const int n = nr * 16 + i;
      t[d * 65 + n] = src[(long)n * 1024 + d];
    }
  }
  __syncthreads();
  __hip_bfloat16* dstb = vtc + (long)bh * 65 * 1024 + n0;
  {
    const int n = tid & 63, dr = tid >> 6;
#pragma unroll
    for (int i = 0; i < 16; ++i) {
      const int dd = dr * 16 + i;
      dstb[(long)dd * 1024 + n] = t[dd * 65 + n];
    }
  }
  if (tid < 64) dstb[(long)64 * 1024 + tid] = (__hip_bfloat16)1.0f;
}

// ---------------------------------------------------------------------------
extern "C" void kernel_launch(void* const* d_in, const int* in_sizes, int n_in,
                              void* d_out, int out_size, void* d_ws,
                              size_t ws_size, hipStream_t stream) {
  const float* x    = (const float*)d_in[0];
  const float* Wq   = (const float*)d_in[1];
  const float* Wk   = (const float*)d_in[2];
  const float* Wv   = (const float*)d_in[3];
  const float* Wo   = (const float*)d_in[4];
  const float* bo   = (const float*)d_in[5];
  const float* proj = (const float*)d_in[6];
  float* out = (float*)d_out;
  char* ws = (char*)d_ws;

  // ws layout (bytes); total 162,545,664 (~155 MiB) — known to fit
  constexpr long o_wqt   = 0;            // 1024x1024x2 = 2,097,152
  constexpr long o_wkt   = 2097152;
  constexpr long o_wvt   = 4194304;
  constexpr long o_wot   = 6291456;
  constexpr long o_projb = 8388608;      // 288x64x2 = 36,864
  constexpr long o_Qb    = 8425472;      // 16384x1024x2 = 33,554,432
  constexpr long o_Kb    = 41979904;     // 33,554,432 (aliased: outm)
  constexpr long o_Vb    = 75534336;     // 33,554,432
  constexpr long o_chunk = 109088768;    // 64x288x1024x2 = 37,748,736 (kpt/qp)
  constexpr long o_vtc   = 146837504;    // 64x65x1024x2 = 8,519,680
  constexpr long o_kvxf  = 155357184;    // 64x65x288x4 = 4,792,320
  constexpr long o_kvxb  = 160149504;    // 64x65x288x2 = 2,396,160

  __hip_bfloat16* wqt   = (__hip_bfloat16*)(ws + o_wqt);
  __hip_bfloat16* wkt   = (__hip_bfloat16*)(ws + o_wkt);
  __hip_bfloat16* wvt   = (__hip_bfloat16*)(ws + o_wvt);
  __hip_bfloat16* wot   = (__hip_bfloat16*)(ws + o_wot);
  __hip_bfloat16* projb = (__hip_bfloat16*)(ws + o_projb);
  __hip_bfloat16* Qb    = (__hip_bfloat16*)(ws + o_Qb);
  __hip_bfloat16* Kb    = (__hip_bfloat16*)(ws + o_Kb);
  __hip_bfloat16* Vb    = (__hip_bfloat16*)(ws + o_Vb);
  __hip_bfloat16* chunk = (__hip_bfloat16*)(ws + o_chunk);
  __hip_bfloat16* vtc   = (__hip_bfloat16*)(ws + o_vtc);
  float*          kvxf  = (float*)(ws + o_kvxf);
  __hip_bfloat16* kvxb  = (__hip_bfloat16*)(ws + o_kvxb);
  __hip_bfloat16* outm  = Kb;  // alias: Kb dead after phase A

  // prep (f32 -> bf16 conversions folded in)
  transpose_w<<<dim3(32, 32), 256, 0, stream>>>(Wq, wqt);
  transpose_w<<<dim3(32, 32), 256, 0, stream>>>(Wk, wkt);
  transpose_w<<<dim3(32, 32), 256, 0, stream>>>(Wv, wvt);
  transpose_w<<<dim3(32, 32), 256, 0, stream>>>(Wo, wot);
  prep_proj<<<72, 256, 0, stream>>>(proj, projb);
  zero_f32<<<(1198080 + 255) / 256, 256, 0, stream>>>(kvxf, 1198080);

  // S1: Q/K/V projections (A = x in f32)
  gemm_nt<0, true><<<dim3(128, 8, 1), 256, 0, stream>>>(
      x, 1024, 0, 0, wqt, 1024, 0, 0, Qb, 1024, 0, 0, 16384, 1024, 1024, nullptr);
  gemm_nt<0, true><<<dim3(128, 8, 1), 256, 0, stream>>>(
      x, 1024, 0, 0, wkt, 1024, 0, 0, Kb, 1024, 0, 0, 16384, 1024, 1024, nullptr);
  gemm_nt<0, true><<<dim3(128, 8, 1), 256, 0, stream>>>(
      x, 1024, 0, 0, wvt, 1024, 0, 0, Vb, 1024, 0, 0, 16384, 1024, 1024, nullptr);

  const long sA_bh  = (long)4096 * 1024;  // Qb/Kb/Vb per-b stride
  const long s_kptc = (long)288 * 1024;   // kptc per-bh
  const long s_vtc  = (long)65 * 1024;
  const long s_kvx  = (long)65 * 288;
  const long s_qpc  = (long)1024 * 288;

  // phase A: kv accumulation over 4 n-chunks
  for (int c = 0; c < 4; ++c) {
    const long co = (long)c * 1024 * 1024;  // chunk offset inside each b
    // S2k: kptc = relu(projb . K_c^T)+eps, rows>=266 -> 0
    gemm_nt<2, false><<<dim3(3, 8, 64), 256, 0, stream>>>(
        projb, 64, 0, 0, Kb + co, 1024, sA_bh, 64, chunk, 1024, 16 * s_kptc,
        s_kptc, 288, 1024, 64, nullptr);
    // vtc = [V_c^T ; ones]
    build_vtc<<<dim3(16, 64), 256, 0, stream>>>(Vb, vtc, c);
    // S3: kvxf += vtc . kptc^T
    gemm_nt<6, false><<<dim3(1, 3, 64), 256, 0, stream>>>(
        vtc, 1024, 16 * s_vtc, s_vtc, chunk, 1024, 16 * s_kptc, s_kptc, kvxf,
        288, 16 * s_kvx, s_kvx, 65, 288, 1024, nullptr);
  }
  finalize_kvx<<<(1198080 + 255) / 256, 256, 0, stream>>>(kvxf, kvxb, 1198080);

  // phase B: qp + attention output per chunk
  for (int c = 0; c < 4; ++c) {
    const long co = (long)c * 1024 * 1024;
    // S2q: qpc = relu(Q_c . projb^T)+eps, cols>=266 -> 0
    gemm_nt<1, false><<<dim3(8, 3, 64), 256, 0, stream>>>(
        Qb + co, 1024, sA_bh, 64, projb, 64, 0, 0, chunk, 288, 16 * s_qpc,
        s_qpc, 1024, 288, 64, nullptr);
    // S4: outm rows = (qpc . kvxb^T)/denom, merged heads
    gemm_nt<4, false><<<dim3(8, 1, 64), 256, 0, stream>>>(
        chunk, 288, 16 * s_qpc, s_qpc, kvxb, 288, 16 * s_kvx, s_kvx,
        outm + co, 1024, sA_bh, 64, 1024, 65, 288, nullptr);
  }

  // S5: out(f32) = outm . wot^T + bo
  gemm_nt<5, false><<<dim3(128, 8, 1), 256, 0, stream>>>(
      outm, 1024, 0, 0, wot, 1024, 0, 0, out, 1024, 0, 0, 16384, 1024, 1024,
      bo);
}

// Round 7
// 834.974 us; speedup vs baseline: 1.1188x; 1.1188x over previous
//
#include <hip/hip_runtime.h>
#include <hip/hip_bf16.h>

// ---------------------------------------------------------------------------
// Performer (FAVOR+) attention, MI355X gfx950.  f32 I/O, bf16 MFMA internals.
// R7: (1) x pre-converted to bf16 (aliases chunk buffer); (2) S1 fused into
// ONE N=3072 GEMM writing Qb/Kb/Vb via split epilogue; (3) global_load_lds
// width-16 staging restored in all GEMMs (m97 structure).
//   prep:  wqkvt(3072x1024)=bf16([Wq|Wk|Wv]^T); wot=bf16(Wo^T); projb padded
//   S1:    [Qb|Kb|Vb](16384x1024 bf16 each) = xb . wqkvt^T   (EPI7)
//   phase A, per n-chunk c (1024 rows x 4):
//     S2k: kptc[bh](288x1024) = relu(projb . K_c^T)+eps, rows>=266->0 (EPI2)
//     vtc[bh](65x1024)        = [V_c^T ; ones]
//     S3:  kvxf[bh](65x288)  += vtc . kptc^T  f32 accumulate (EPI6)
//   finalize: kvxb = bf16(kvxf)
//   phase B, per chunk c:
//     S2q: qpc[bh](1024x288) = relu(Q_c . projb^T)+eps, cols>=266->0 (EPI1)
//     S4:  outm rows c       = (qpc . kvxb^T)/denom, merged heads (EPI4)
//   S5:    out(f32) = outm . wot^T + bo (EPI5)
// Aliases: xb=chunk (dead before phase A); outm=Kb (dead after phase A);
// qpc=kptc=chunk.  ws total 162.5 MB (proven to fit in R6).
// GEMM: NT bf16 MFMA 16x16x32, 128x128 tile, 256 thr, BK=32, chunk-major LDS.
// ---------------------------------------------------------------------------

typedef __bf16 bf16x8 __attribute__((ext_vector_type(8)));
typedef float  f32x4  __attribute__((ext_vector_type(4)));

#define EPS_F 1e-3f

__device__ __forceinline__ void gld16(const void* g, void* l) {
  __builtin_amdgcn_global_load_lds(
      (const __attribute__((address_space(1))) void*)g,
      (__attribute__((address_space(3))) void*)l, 16, 0, 0);
}

// EPI: 1 relu+eps col>=266->0 | 2 relu+eps row>=266->0 | 4 /denom(col 64),
// bf16 merged-head | 5 +bias f32 | 6 f32 += | 7 QKV split bf16 store
template <int EPI>
__global__ void __launch_bounds__(256, 2)
gemm_nt(const __hip_bfloat16* __restrict__ A, long lda, long sAb, long sAh,
        const __hip_bfloat16* __restrict__ Bt, long ldb, long sBb, long sBh,
        void* __restrict__ Cp, long ldc, long sCb, long sCh,
        int M, int N, int K, const float* __restrict__ bias) {
  __shared__ __align__(16) __hip_bfloat16 As[4096];  // 128x32 bf16, chunk-major
  __shared__ __align__(16) __hip_bfloat16 Bs[4096];
  __shared__ float Dsh[128];  // EPI4 denominator broadcast

  const int tid  = threadIdx.x;
  const int lane = tid & 63;
  const int wave = tid >> 6;
  const int quad = lane >> 4;
  const int l15  = lane & 15;
  const int wm   = wave >> 1;
  const int wn   = wave & 1;
  const int m0   = blockIdx.x * 128;
  const int n0   = blockIdx.y * 128;
  const int bz   = blockIdx.z;
  const int bb   = bz >> 4, hh = bz & 15;

  A  += (long)bb * sAb + (long)hh * sAh;
  Bt += (long)bb * sBb + (long)hh * sBh;

  // staging: thread t stages plane cc=t>>7 (and cc+2), row mr=t&127
  const int  mr   = tid & 127;
  const int  cc   = tid >> 7;  // 0/1
  const long aoff = (long)min(m0 + mr, M - 1) * lda + cc * 8;  // row-clamped
  const long boff = (long)min(n0 + mr, N - 1) * ldb + cc * 8;
  char* AsB = (char*)As;
  char* BsB = (char*)Bs;
  const int ldst = tid * 16;

  f32x4 acc[4][4] = {};

  for (int k0 = 0; k0 < K; k0 += 32) {
    gld16(A + aoff + k0,       AsB + ldst);
    gld16(A + aoff + k0 + 16,  AsB + ldst + 4096);
    gld16(Bt + boff + k0,      BsB + ldst);
    gld16(Bt + boff + k0 + 16, BsB + ldst + 4096);
    __syncthreads();  // drains vmcnt -> LDS valid

    const char* ap = (const char*)As + quad * 2048 + (wm * 64 + l15) * 16;
    const char* bp = (const char*)Bs + quad * 2048 + (wn * 64 + l15) * 16;
    bf16x8 af[4], bfr[4];
#pragma unroll
    for (int it = 0; it < 4; ++it) af[it] = *(const bf16x8*)(ap + it * 256);
#pragma unroll
    for (int jt = 0; jt < 4; ++jt) bfr[jt] = *(const bf16x8*)(bp + jt * 256);
#pragma unroll
    for (int it = 0; it < 4; ++it)
#pragma unroll
      for (int jt = 0; jt < 4; ++jt)
        acc[it][jt] = __builtin_amdgcn_mfma_f32_16x16x32_bf16(
            af[it], bfr[jt], acc[it][jt], 0, 0, 0);
    __syncthreads();
  }

  const long cbase = (long)bb * sCb + (long)hh * sCh;

  if constexpr (EPI == 4) {
    // denominator = col 64 -> wave wn==1, tile jt=0, lanes l15==0
    if (wn == 1 && l15 == 0) {
#pragma unroll
      for (int it = 0; it < 4; ++it)
#pragma unroll
        for (int i = 0; i < 4; ++i)
          Dsh[wm * 64 + it * 16 + quad * 4 + i] = acc[it][0][i];
    }
    __syncthreads();
    if (wn == 0) {  // cols 0..63 = HC dims
      __hip_bfloat16* C = (__hip_bfloat16*)Cp;
#pragma unroll
      for (int it = 0; it < 4; ++it) {
#pragma unroll
        for (int i = 0; i < 4; ++i) {
          const int   row = wm * 64 + it * 16 + quad * 4 + i;
          const float den = Dsh[row];
          const float dinv = (den > 1e-30f) ? (1.0f / den) : 0.0f;
          const long  gm   = m0 + row;
#pragma unroll
          for (int jt = 0; jt < 4; ++jt) {
            const int col = jt * 16 + l15;
            C[cbase + gm * ldc + col] =
                (__hip_bfloat16)(acc[it][jt][i] * dinv);
          }
        }
      }
    }
  } else {
#pragma unroll
    for (int it = 0; it < 4; ++it) {
#pragma unroll
      for (int jt = 0; jt < 4; ++jt) {
#pragma unroll
        for (int i = 0; i < 4; ++i) {
          const int row = wm * 64 + it * 16 + quad * 4 + i;
          const int col = wn * 64 + jt * 16 + l15;
          const int gm = m0 + row, gn = n0 + col;
          if (gm < M && gn < N) {
            float v = acc[it][jt][i];
            if constexpr (EPI == 7) {
              // split into Qb/Kb/Vb (contiguous 16384x1024 slabs after Cp)
              const long q = gn >> 10;
              const long r = gn & 1023;
              ((__hip_bfloat16*)Cp)[q * 16777216 + (long)gm * 1024 + r] =
                  (__hip_bfloat16)v;
            } else {
              if constexpr (EPI == 1) v = (gn < 266) ? (fmaxf(v, 0.f) + EPS_F) : 0.f;
              if constexpr (EPI == 2) v = (gm < 266) ? (fmaxf(v, 0.f) + EPS_F) : 0.f;
              if constexpr (EPI == 6) {
                ((float*)Cp)[cbase + (long)gm * ldc + gn] += v;
              } else if constexpr (EPI == 5) {
                ((float*)Cp)[cbase + (long)gm * ldc + gn] = v + bias[gn];
              } else {
                ((__hip_bfloat16*)Cp)[cbase + (long)gm * ldc + gn] =
                    (__hip_bfloat16)v;
              }
            }
          }
        }
      }
    }
  }
}

// xb = bf16(x), 8 elements/thread
__global__ void cvt_x(const float* __restrict__ x,
                      __hip_bfloat16* __restrict__ xb) {
  const long i = ((long)blockIdx.x * 256 + threadIdx.x) * 8;
  const float4 f0 = *(const float4*)(x + i);
  const float4 f1 = *(const float4*)(x + i + 4);
  union { __hip_bfloat16 h[8]; uint4 u; } r;
  r.h[0] = (__hip_bfloat16)f0.x; r.h[1] = (__hip_bfloat16)f0.y;
  r.h[2] = (__hip_bfloat16)f0.z; r.h[3] = (__hip_bfloat16)f0.w;
  r.h[4] = (__hip_bfloat16)f1.x; r.h[5] = (__hip_bfloat16)f1.y;
  r.h[6] = (__hip_bfloat16)f1.z; r.h[7] = (__hip_bfloat16)f1.w;
  *(uint4*)(xb + i) = r.u;
}

// dst[n*1024 + k] = bf16(src[k*1024 + n])  (1024x1024, f32 -> bf16)
__global__ void transpose_w(const float* __restrict__ src,
                            __hip_bfloat16* __restrict__ dst) {
  __shared__ float t[32][33];
  const int k0 = blockIdx.x * 32, n0 = blockIdx.y * 32;
  const int tx = threadIdx.x & 31, ty = threadIdx.x >> 5;
#pragma unroll
  for (int i = 0; i < 4; ++i)
    t[ty + i * 8][tx] = src[(long)(k0 + ty + i * 8) * 1024 + n0 + tx];
  __syncthreads();
#pragma unroll
  for (int i = 0; i < 4; ++i)
    dst[(long)(n0 + ty + i * 8) * 1024 + k0 + tx] =
        (__hip_bfloat16)t[tx][ty + i * 8];
}

// projb (288x64 bf16): rows<266 = bf16(proj), rows 266..287 exact zero.
__global__ void prep_proj(const float* __restrict__ proj,
                          __hip_bfloat16* __restrict__ projb) {
  const int i = blockIdx.x * 256 + threadIdx.x;
  if (i < 288 * 64) {
    const int r = i >> 6;
    __hip_bfloat16 v = (__hip_bfloat16)0.f;
    if (r < 266) v = (__hip_bfloat16)proj[i];
    projb[i] = v;
  }
}

__global__ void zero_f32(float* __restrict__ p, int n) {
  const int i = blockIdx.x * 256 + threadIdx.x;
  if (i < n) p[i] = 0.f;
}

__global__ void finalize_kvx(const float* __restrict__ kvxf,
                             __hip_bfloat16* __restrict__ kvxb, int n) {
  const int i = blockIdx.x * 256 + threadIdx.x;
  if (i < n) kvxb[i] = (__hip_bfloat16)kvxf[i];
}

// vtc[bh](65x1024) = [V_chunk^T ; ones] from Vb rows c*1024..+1024
__global__ void build_vtc(const __hip_bfloat16* __restrict__ Vb,
                          __hip_bfloat16* __restrict__ vtc, int c) {
  __shared__ __hip_bfloat16 t[64 * 65];
  const int bh = blockIdx.y, n0 = blockIdx.x * 64;
  const int b = bh >> 4, h = bh & 15;
  const int tid = threadIdx.x;
  const __hip_bfloat16* src =
      Vb + ((long)b * 4096 + (long)c * 1024 + n0) * 1024 + h * 64;
  {
    const int d = tid & 63, nr = tid >> 6;
#pragma unroll
    for (int i = 0; i < 16; ++i) {
      const int n = nr * 16 + i;
      t[d * 65 + n] = src[(long)n * 1024 + d];
    }
  }
  __syncthreads();
  __hip_bfloat16* dstb = vtc + (long)bh * 65 * 1024 + n0;
  {
    const int n = tid & 63, dr = tid >> 6;
#pragma unroll
    for (int i = 0; i < 16; ++i) {
      const int dd = dr * 16 + i;
      dstb[(long)dd * 1024 + n] = t[dd * 65 + n];
    }
  }
  if (tid < 64) dstb[(long)64 * 1024 + tid] = (__hip_bfloat16)1.0f;
}

// ---------------------------------------------------------------------------
extern "C" void kernel_launch(void* const* d_in, const int* in_sizes, int n_in,
                              void* d_out, int out_size, void* d_ws,
                              size_t ws_size, hipStream_t stream) {
  const float* x    = (const float*)d_in[0];
  const float* Wq   = (const float*)d_in[1];
  const float* Wk   = (const float*)d_in[2];
  const float* Wv   = (const float*)d_in[3];
  const float* Wo   = (const float*)d_in[4];
  const float* bo   = (const float*)d_in[5];
  const float* proj = (const float*)d_in[6];
  float* out = (float*)d_out;
  char* ws = (char*)d_ws;

  // ws layout (bytes); total 162,545,664 (~155 MiB) — proven fit in R6
  constexpr long o_wqkvt = 0;            // 3072x1024x2 = 6,291,456
  constexpr long o_wot   = 6291456;      // 2,097,152
  constexpr long o_projb = 8388608;      // 36,864
  constexpr long o_Qb    = 8425472;      // 33,554,432
  constexpr long o_Kb    = 41979904;     // 33,554,432 (contiguous; alias outm)
  constexpr long o_Vb    = 75534336;     // 33,554,432 (contiguous)
  constexpr long o_chunk = 109088768;    // 37,748,736 (kptc/qpc; alias xb)
  constexpr long o_vtc   = 146837504;    // 8,519,680
  constexpr long o_kvxf  = 155357184;    // 4,792,320
  constexpr long o_kvxb  = 160149504;    // 2,396,160

  __hip_bfloat16* wqkvt = (__hip_bfloat16*)(ws + o_wqkvt);
  __hip_bfloat16* wot   = (__hip_bfloat16*)(ws + o_wot);
  __hip_bfloat16* projb = (__hip_bfloat16*)(ws + o_projb);
  __hip_bfloat16* Qb    = (__hip_bfloat16*)(ws + o_Qb);
  __hip_bfloat16* Kb    = (__hip_bfloat16*)(ws + o_Kb);
  __hip_bfloat16* Vb    = (__hip_bfloat16*)(ws + o_Vb);
  __hip_bfloat16* chunk = (__hip_bfloat16*)(ws + o_chunk);
  __hip_bfloat16* vtc   = (__hip_bfloat16*)(ws + o_vtc);
  float*          kvxf  = (float*)(ws + o_kvxf);
  __hip_bfloat16* kvxb  = (__hip_bfloat16*)(ws + o_kvxb);
  __hip_bfloat16* xb    = chunk;  // alias: dead before phase A overwrites
  __hip_bfloat16* outm  = Kb;     // alias: Kb dead after phase A

  // prep
  cvt_x<<<8192, 256, 0, stream>>>(x, xb);
  transpose_w<<<dim3(32, 32), 256, 0, stream>>>(Wq, wqkvt);
  transpose_w<<<dim3(32, 32), 256, 0, stream>>>(Wk, wqkvt + 1024 * 1024);
  transpose_w<<<dim3(32, 32), 256, 0, stream>>>(Wv, wqkvt + 2 * 1024 * 1024);
  transpose_w<<<dim3(32, 32), 256, 0, stream>>>(Wo, wot);
  prep_proj<<<72, 256, 0, stream>>>(proj, projb);
  zero_f32<<<(1198080 + 255) / 256, 256, 0, stream>>>(kvxf, 1198080);

  // S1 fused: [Qb|Kb|Vb] = xb . wqkvt^T
  gemm_nt<7><<<dim3(128, 24, 1), 256, 0, stream>>>(
      xb, 1024, 0, 0, wqkvt, 1024, 0, 0, Qb, 0, 0, 0, 16384, 3072, 1024,
      nullptr);

  const long sA_bh  = (long)4096 * 1024;  // Qb/Kb/Vb per-b stride
  const long s_kptc = (long)288 * 1024;
  const long s_vtc  = (long)65 * 1024;
  const long s_kvx  = (long)65 * 288;
  const long s_qpc  = (long)1024 * 288;

  // phase A: kv accumulation over 4 n-chunks
  for (int c = 0; c < 4; ++c) {
    const long co = (long)c * 1024 * 1024;
    gemm_nt<2><<<dim3(3, 8, 64), 256, 0, stream>>>(
        projb, 64, 0, 0, Kb + co, 1024, sA_bh, 64, chunk, 1024, 16 * s_kptc,
        s_kptc, 288, 1024, 64, nullptr);
    build_vtc<<<dim3(16, 64), 256, 0, stream>>>(Vb, vtc, c);
    gemm_nt<6><<<dim3(1, 3, 64), 256, 0, stream>>>(
        vtc, 1024, 16 * s_vtc, s_vtc, chunk, 1024, 16 * s_kptc, s_kptc, kvxf,
        288, 16 * s_kvx, s_kvx, 65, 288, 1024, nullptr);
  }
  finalize_kvx<<<(1198080 + 255) / 256, 256, 0, stream>>>(kvxf, kvxb, 1198080);

  // phase B: qp + attention output per chunk
  for (int c = 0; c < 4; ++c) {
    const long co = (long)c * 1024 * 1024;
    gemm_nt<1><<<dim3(8, 3, 64), 256, 0, stream>>>(
        Qb + co, 1024, sA_bh, 64, projb, 64, 0, 0, chunk, 288, 16 * s_qpc,
        s_qpc, 1024, 288, 64, nullptr);
    gemm_nt<4><<<dim3(8, 1, 64), 256, 0, stream>>>(
        chunk, 288, 16 * s_qpc, s_qpc, kvxb, 288, 16 * s_kvx, s_kvx,
        outm + co, 1024, sA_bh, 64, 1024, 65, 288, nullptr);
  }

  // S5: out(f32) = outm . wot^T + bo
  gemm_nt<5><<<dim3(128, 8, 1), 256, 0, stream>>>(
      outm, 1024, 0, 0, wot, 1024, 0, 0, out, 1024, 0, 0, 16384, 1024, 1024,
      bo);
}